// Round 4
// baseline (144.237 us; speedup 1.0000x reference)
//
#include <hip/hip_runtime.h>
#include <hip/hip_bf16.h>

// Capsule dynamic routing, factored to avoid materializing u_hat (268 MB).
// B=64, N=2048 input capsules, D=64 in-dim, I=32 out capsules, J=16 out dim.
//   o[b,i,:]  = (sum_n c[b,i,n] * u[b,n,:]) @ W_i
//   b[b,i,n]  = u[b,n,:] . w~[b,i,:],  w~ = W_i @ l2norm(o)
// Round 4: occupancy fix. kbig: 512-thr blocks, i-split softmax via lane-pair
// shuffle, c stored transposed in LDS for b128 phase-2 reads. 16 waves/CU
// (VGPR-capped) vs 6 before.

#define BB 64
#define NN 2048
#define DD 64
#define II 32
#define JJ 16
#define RR 256   // rows per kbig block

// ---------------- kernel 1: s[b,d] = sum_n u[b,n,d] ----------------
__global__ __launch_bounds__(256) void ksum(const float* __restrict__ u,
                                            float* __restrict__ s) {
    int b = blockIdx.y;
    int cb = blockIdx.x;                    // 0..31, 64 rows each
    int d = threadIdx.x & 63;
    int g = threadIdx.x >> 6;               // 0..3
    const float* ub = u + (size_t)b * NN * DD + (size_t)(cb * 64) * DD;
    float acc = 0.f;
    #pragma unroll 4
    for (int r = g; r < 64; r += 4)
        acc += ub[(size_t)r * DD + d];      // 256B/wave coalesced
    __shared__ float red[4][64];
    red[g][d] = acc;
    __syncthreads();
    if (g == 0)
        atomicAdd(&s[b * DD + d], red[0][d] + red[1][d] + red[2][d] + red[3][d]);
}

// ---------------- small kernel: per-(b,i) o, normalize, w~ (or squash->out) ----
template <int MODE>
__global__ __launch_bounds__(512) void ksmall(const float* __restrict__ src,
                                              const float* __restrict__ W,
                                              float* __restrict__ w_out,
                                              float* __restrict__ out) {
    int b = blockIdx.x;
    int tid = threadIdx.x;                  // 512 = 32 capsules x 16 dims
    int i = tid >> 4;
    int j = tid & 15;
    const float* trow = (MODE == 0) ? (src + (size_t)b * DD)
                                    : (src + ((size_t)b * II + i) * DD);
    float o = 0.f;
    #pragma unroll 8
    for (int d = 0; d < DD; ++d)
        o += trow[d] * W[d * (II * JJ) + i * JJ + j];   // W reads coalesced over tid
    if (MODE == 0) o *= (1.0f / 32.0f);

    float ss = o * o;
    #pragma unroll
    for (int off = 8; off >= 1; off >>= 1)
        ss += __shfl_xor(ss, off, 16);

    if (MODE == 2) {
        float s2 = ss + 1e-7f;                       // K.epsilon
        float scale = sqrtf(s2) / (0.5f + s2);       // squash
        out[((size_t)b * II + i) * JJ + j] = scale * o;
        return;
    }

    float norm = sqrtf(fmaxf(ss, 1e-12f));           // tf l2_normalize
    float ov = o / norm;
    __shared__ float osh[II][JJ];
    osh[i][j] = ov;
    __syncthreads();
    #pragma unroll
    for (int k = 0; k < 4; ++k) {
        int d = j + 16 * k;
        float acc = 0.f;
        #pragma unroll
        for (int jj = 0; jj < 16; ++jj)
            acc += W[d * (II * JJ) + i * JJ + jj] * osh[i][jj];
        w_out[((size_t)b * II + i) * DD + d] = acc;
    }
}

// ---------------- big kernel: one routing pass ----------------
// Phase 1: lane-pair (n, h): h-half of 16 capsule dots per row, softmax via
//          shfl_xor(1). c written TRANSPOSED csh[i][n].
// Phase 2: thread (i, dg): t[i][4d] over 256 rows, c via broadcast b128.
__global__ __launch_bounds__(512, 4) void kbig(const float* __restrict__ u,
                                               const float* __restrict__ w,
                                               float* __restrict__ t) {
    int b = blockIdx.y;
    int chunk = blockIdx.x;                 // 0..7, RR rows each
    const float* ub = u + (size_t)b * NN * DD;
    const float* wb = w + (size_t)b * II * DD;

    __shared__ float wsh[II][68];           // 8.7 KB, 16B-aligned rows
    __shared__ float csh[II][RR + 4];       // c^T, 33.3 KB, 1040B rows (16B-aligned)
    int tid = threadIdx.x;

    for (int idx = tid; idx < II * DD; idx += 512)
        wsh[idx >> 6][idx & 63] = wb[idx];
    __syncthreads();

    // ---- phase 1 ----
    int n = tid >> 1;                       // 0..255
    int h = tid & 1;                        // i-half: capsules [16h, 16h+16)
    const float* urow = ub + (size_t)(chunk * RR + n) * DD;
    float bacc[16];
    #pragma unroll
    for (int il = 0; il < 16; ++il) bacc[il] = 0.f;
    #pragma unroll
    for (int d0 = 0; d0 < DD; d0 += 4) {
        float4 u4 = *reinterpret_cast<const float4*>(urow + d0);
        #pragma unroll
        for (int il = 0; il < 16; ++il) {
            float4 w4 = *reinterpret_cast<const float4*>(&wsh[h * 16 + il][d0]);
            bacc[il] += u4.x * w4.x + u4.y * w4.y + u4.z * w4.z + u4.w * w4.w;
        }
    }
    // softmax over 32 = own 16 + partner's 16 (adjacent lane)
    float m = bacc[0];
    #pragma unroll
    for (int il = 1; il < 16; ++il) m = fmaxf(m, bacc[il]);
    m = fmaxf(m, __shfl_xor(m, 1));
    float sum = 0.f;
    #pragma unroll
    for (int il = 0; il < 16; ++il) { bacc[il] = __expf(bacc[il] - m); sum += bacc[il]; }
    sum += __shfl_xor(sum, 1);
    float inv = 1.f / sum;
    #pragma unroll
    for (int il = 0; il < 16; ++il)
        csh[h * 16 + il][n] = bacc[il] * inv;   // 2-way bank alias: free
    __syncthreads();

    // ---- phase 2: t[i][dg*4..+3] += sum_n csh[i][n] * u[n][dg*4..] ----
    int i = tid >> 4;                       // 0..31
    int dg = tid & 15;                      // d-group of 4
    const float* ubase = ub + (size_t)(chunk * RR) * DD + dg * 4;
    float4 acc = {0.f, 0.f, 0.f, 0.f};
    #pragma unroll 2
    for (int n0 = 0; n0 < RR; n0 += 4) {
        float4 c4 = *reinterpret_cast<const float4*>(&csh[i][n0]);  // broadcast b128
        float4 u0 = *reinterpret_cast<const float4*>(ubase + (size_t)(n0 + 0) * DD);
        float4 u1 = *reinterpret_cast<const float4*>(ubase + (size_t)(n0 + 1) * DD);
        float4 u2 = *reinterpret_cast<const float4*>(ubase + (size_t)(n0 + 2) * DD);
        float4 u3 = *reinterpret_cast<const float4*>(ubase + (size_t)(n0 + 3) * DD);
        acc.x += c4.x * u0.x + c4.y * u1.x + c4.z * u2.x + c4.w * u3.x;
        acc.y += c4.x * u0.y + c4.y * u1.y + c4.z * u2.y + c4.w * u3.y;
        acc.z += c4.x * u0.z + c4.y * u1.z + c4.z * u2.z + c4.w * u3.z;
        acc.w += c4.x * u0.w + c4.y * u1.w + c4.z * u2.w + c4.w * u3.w;
    }
    float* tp = &t[((size_t)b * II + i) * DD + dg * 4];
    atomicAdd(tp + 0, acc.x);
    atomicAdd(tp + 1, acc.y);
    atomicAdd(tp + 2, acc.z);
    atomicAdd(tp + 3, acc.w);
}

extern "C" void kernel_launch(void* const* d_in, const int* in_sizes, int n_in,
                              void* d_out, int out_size, void* d_ws, size_t ws_size,
                              hipStream_t stream) {
    const float* u = (const float*)d_in[0];     // (64, 2048, 64)
    const float* W = (const float*)d_in[1];     // (1, 64, 512)
    float* out = (float*)d_out;                 // (64, 32, 16)
    float* ws = (float*)d_ws;

    float* s  = ws;                             // 4096 floats
    float* t1 = ws + 4096;                      // 131072 floats
    float* t2 = ws + 4096 + 131072;             // 131072 floats
    float* wv = ws + 4096 + 2 * 131072;         // 131072 floats (w~)

    // zero the atomically-accumulated buffers (harness does not re-poison)
    hipMemsetAsync(ws, 0, (4096 + 2 * 131072) * sizeof(float), stream);

    ksum<<<dim3(32, BB), 256, 0, stream>>>(u, s);
    ksmall<0><<<BB, 512, 0, stream>>>(s, W, wv, nullptr);   // iter0: uniform c
    kbig<<<dim3(NN / RR, BB), 512, 0, stream>>>(u, wv, t1); // iter1
    ksmall<1><<<BB, 512, 0, stream>>>(t1, W, wv, nullptr);
    kbig<<<dim3(NN / RR, BB), 512, 0, stream>>>(u, wv, t2); // iter2
    ksmall<2><<<BB, 512, 0, stream>>>(t2, W, nullptr, out); // squash -> out
}

// Round 5
// 118.569 us; speedup vs baseline: 1.2165x; 1.2165x over previous
//
#include <hip/hip_runtime.h>
#include <hip/hip_bf16.h>

// Capsule dynamic routing, factored to avoid materializing u_hat (268 MB).
// B=64, N=2048, D=64, I=32 out capsules, J=16 out dim.
//   o[b,i,:]  = (sum_n c[b,i,n] * u[b,n,:]) @ W_i
//   b[b,i,n]  = u[b,n,:] . w~[b,i,:],  w~ = W_i @ l2norm(o)
// Round 5: register-blocked kbig. Phase1: 2 rows x 16 caps per thread
// (8 FMA per LDS broadcast). Phase2: wave-row-stationary, lane=column,
// 32-reg t accumulator, full-wave-broadcast c reads, coalesced u reads.
// No tight VGPR cap (r4 lesson: (512,4) -> 40 VGPR killed ILP).

#define BB 64
#define NN 2048
#define DD 64
#define II 32
#define JJ 16
#define RR 256   // rows per kbig block

// ---------------- kernel 1: s[b,d] = sum_n u[b,n,d] ----------------
__global__ __launch_bounds__(256) void ksum(const float* __restrict__ u,
                                            float* __restrict__ s) {
    int b = blockIdx.y;
    int cb = blockIdx.x;                    // 0..31, 64 rows each
    int d = threadIdx.x & 63;
    int g = threadIdx.x >> 6;               // 0..3
    const float* ub = u + (size_t)b * NN * DD + (size_t)(cb * 64) * DD;
    float acc = 0.f;
    #pragma unroll 4
    for (int r = g; r < 64; r += 4)
        acc += ub[(size_t)r * DD + d];      // 256B/wave coalesced
    __shared__ float red[4][64];
    red[g][d] = acc;
    __syncthreads();
    if (g == 0)
        atomicAdd(&s[b * DD + d], red[0][d] + red[1][d] + red[2][d] + red[3][d]);
}

// ---------------- small kernel: per-(b,i) o, normalize, w~ (or squash->out) ----
template <int MODE>
__global__ __launch_bounds__(512) void ksmall(const float* __restrict__ src,
                                              const float* __restrict__ W,
                                              float* __restrict__ w_out,
                                              float* __restrict__ out) {
    int b = blockIdx.x;
    int tid = threadIdx.x;                  // 512 = 32 capsules x 16 dims
    int i = tid >> 4;
    int j = tid & 15;
    const float* trow = (MODE == 0) ? (src + (size_t)b * DD)
                                    : (src + ((size_t)b * II + i) * DD);
    float o = 0.f;
    #pragma unroll 8
    for (int d = 0; d < DD; ++d)
        o += trow[d] * W[d * (II * JJ) + i * JJ + j];
    if (MODE == 0) o *= (1.0f / 32.0f);

    float ss = o * o;
    #pragma unroll
    for (int off = 8; off >= 1; off >>= 1)
        ss += __shfl_xor(ss, off, 16);

    if (MODE == 2) {
        float s2 = ss + 1e-7f;                       // K.epsilon
        float scale = sqrtf(s2) / (0.5f + s2);       // squash
        out[((size_t)b * II + i) * JJ + j] = scale * o;
        return;
    }

    float norm = sqrtf(fmaxf(ss, 1e-12f));           // tf l2_normalize
    float ov = o / norm;
    __shared__ float osh[II][JJ];
    osh[i][j] = ov;
    __syncthreads();
    #pragma unroll
    for (int k = 0; k < 4; ++k) {
        int d = j + 16 * k;
        float acc = 0.f;
        #pragma unroll
        for (int jj = 0; jj < 16; ++jj)
            acc += W[d * (II * JJ) + i * JJ + jj] * osh[i][jj];
        w_out[((size_t)b * II + i) * DD + d] = acc;
    }
}

// ---------------- big kernel: one routing pass ----------------
__global__ __launch_bounds__(256, 2) void kbig(const float* __restrict__ u,
                                               const float* __restrict__ w,
                                               float* __restrict__ t) {
    int b = blockIdx.y;
    int chunk = blockIdx.x;                 // 0..7, RR rows each
    const float* ub = u + (size_t)b * NN * DD;
    const float* wb = w + (size_t)b * II * DD;

    __shared__ __align__(16) float wsh[II][68];        // 8.7 KB
    __shared__ __align__(16) float csh[II][RR + 4];    // c^T, 33.3 KB
    int tid = threadIdx.x;

    for (int idx = tid; idx < II * DD; idx += 256)
        wsh[idx >> 6][idx & 63] = wb[idx];
    __syncthreads();

    // ---- phase 1: thread (p,h): rows 2p,2p+1; capsules [16h,16h+16) ----
    int h = tid & 1;
    int p = tid >> 1;                       // 0..127
    int nbase = chunk * RR + 2 * p;
    const float* ra = ub + (size_t)nbase * DD;
    const float* rb = ra + DD;
    float bacc[2][16];
    #pragma unroll
    for (int il = 0; il < 16; ++il) { bacc[0][il] = 0.f; bacc[1][il] = 0.f; }

    #pragma unroll 4
    for (int d0 = 0; d0 < DD; d0 += 4) {
        float4 ua = *reinterpret_cast<const float4*>(ra + d0);
        float4 ub4 = *reinterpret_cast<const float4*>(rb + d0);
        #pragma unroll
        for (int il = 0; il < 16; ++il) {
            float4 w4 = *reinterpret_cast<const float4*>(&wsh[h * 16 + il][d0]);
            bacc[0][il] += ua.x * w4.x + ua.y * w4.y + ua.z * w4.z + ua.w * w4.w;
            bacc[1][il] += ub4.x * w4.x + ub4.y * w4.y + ub4.z * w4.z + ub4.w * w4.w;
        }
    }

    // softmax over 32 = own 16 + partner's 16 (adjacent lane, xor 1)
    #pragma unroll
    for (int r = 0; r < 2; ++r) {
        float m = bacc[r][0];
        #pragma unroll
        for (int il = 1; il < 16; ++il) m = fmaxf(m, bacc[r][il]);
        m = fmaxf(m, __shfl_xor(m, 1));
        float sum = 0.f;
        #pragma unroll
        for (int il = 0; il < 16; ++il) { bacc[r][il] = __expf(bacc[r][il] - m); sum += bacc[r][il]; }
        sum += __shfl_xor(sum, 1);
        float inv = 1.f / sum;
        #pragma unroll
        for (int il = 0; il < 16; ++il)
            csh[h * 16 + il][2 * p + r] = bacc[r][il] * inv;
    }
    __syncthreads();

    // ---- phase 2: lane = column d; wave owns 64 rows; t in 32 regs ----
    int d = tid & 63;
    int wv = tid >> 6;                      // 0..3
    const float* up = ub + (size_t)(chunk * RR + wv * 64) * DD + d;
    float tacc[32];
    #pragma unroll
    for (int i = 0; i < II; ++i) tacc[i] = 0.f;

    for (int n0 = 0; n0 < 64; n0 += 4) {
        float u0 = up[(size_t)(n0 + 0) * DD];   // 256B/wave coalesced
        float u1 = up[(size_t)(n0 + 1) * DD];
        float u2 = up[(size_t)(n0 + 2) * DD];
        float u3 = up[(size_t)(n0 + 3) * DD];
        int nn = wv * 64 + n0;
        #pragma unroll
        for (int i = 0; i < II; ++i) {
            float4 c4 = *reinterpret_cast<const float4*>(&csh[i][nn]);  // wave-broadcast
            tacc[i] += c4.x * u0 + c4.y * u1 + c4.z * u2 + c4.w * u3;
        }
    }
    float* tb = t + ((size_t)b * II) * DD + d;
    #pragma unroll
    for (int i = 0; i < II; ++i)
        atomicAdd(tb + (size_t)i * DD, tacc[i]);    // coalesced per i
}

extern "C" void kernel_launch(void* const* d_in, const int* in_sizes, int n_in,
                              void* d_out, int out_size, void* d_ws, size_t ws_size,
                              hipStream_t stream) {
    const float* u = (const float*)d_in[0];     // (64, 2048, 64)
    const float* W = (const float*)d_in[1];     // (1, 64, 512)
    float* out = (float*)d_out;                 // (64, 32, 16)
    float* ws = (float*)d_ws;

    float* s  = ws;                             // 4096 floats
    float* t1 = ws + 4096;                      // 131072 floats
    float* t2 = ws + 4096 + 131072;             // 131072 floats
    float* wv = ws + 4096 + 2 * 131072;         // 131072 floats (w~)

    // zero the atomically-accumulated buffers (harness does not re-poison)
    hipMemsetAsync(ws, 0, (4096 + 2 * 131072) * sizeof(float), stream);

    ksum<<<dim3(32, BB), 256, 0, stream>>>(u, s);
    ksmall<0><<<BB, 512, 0, stream>>>(s, W, wv, nullptr);   // iter0: uniform c
    kbig<<<dim3(NN / RR, BB), 256, 0, stream>>>(u, wv, t1); // iter1
    ksmall<1><<<BB, 512, 0, stream>>>(t1, W, wv, nullptr);
    kbig<<<dim3(NN / RR, BB), 256, 0, stream>>>(u, wv, t2); // iter2
    ksmall<2><<<BB, 512, 0, stream>>>(t2, W, nullptr, out); // squash -> out
}